// Round 5
// baseline (318.484 us; speedup 1.0000x reference)
//
#include <hip/hip_runtime.h>

// ---------------------------------------------------------------------------
// TransNetSweepingExplRhs — analytic reduction (derivation in R1/R2):
//   h = x@W_in^T + b_in ; th = tanh(h); r1u = h + 0.1 b1
//   Q_i = I/11 - (0.01/121) W_i^T W_i      (1-term Neumann inverse)
//   b1v = 11 th + 0.1 (r1u@W1); y1v = b1v@Q1
//   r2u = r1u - 0.1 (y1v@W1^T) + 0.1 b2
//   b2v = 10 th + y1v + 0.1 (r2u@W2); y2v = b2v@Q2
//   y2u = r2u - 0.1 (y2v@W2^T);  out = softmax(y2u@W_out^T + b_out)
// R5: GEMM = NO-LDS register-fragment loop. Fragments loaded straight from
// global (L1/L2-resident weights), 4-slot rotating buffer, distance-3
// prefetch, zero barriers -> counted vmcnt pipeline, no drain stalls.
// XCD-sharded tile map (b&7 = XCD) keeps per-XCD slice in its 4MB L2.
// ---------------------------------------------------------------------------

typedef short bf16x8 __attribute__((ext_vector_type(8)));
typedef float f32x4 __attribute__((ext_vector_type(4)));

#define M1 1048576

__device__ __forceinline__ unsigned short f2b(float f) {
  union { float f; unsigned int u; } v; v.f = f;
  unsigned int u = v.u;
  return (unsigned short)((u + 0x7FFFu + ((u >> 16) & 1u)) >> 16);
}

__device__ __forceinline__ void ldfrag(const unsigned short* Ar0,
                                       const unsigned short* Ar1,
                                       const unsigned short* Br0,
                                       const unsigned short* Br1,
                                       int kt, bf16x8* af, bf16x8* bf) {
  const int o = kt * 32;
  af[0] = *reinterpret_cast<const bf16x8*>(Ar0 + o);
  af[1] = *reinterpret_cast<const bf16x8*>(Ar1 + o);
  bf[0] = *reinterpret_cast<const bf16x8*>(Br0 + o);
  bf[1] = *reinterpret_cast<const bf16x8*>(Br1 + o);
}

// C[m,n] = sum_k A[m,k]*B[n,k], K=1024, tile 64x64 at (bx,by).
// 4 waves (2x2), wave tile 32x32, fragments direct-from-global.
__device__ __forceinline__ void gemm64(
    const unsigned short* __restrict__ A, const unsigned short* __restrict__ B,
    int bx, int by, int mode,
    const float* bias0, const float* bias1,
    const float* src0, const float* src1,
    float* dstf0, float* dstf1, unsigned short* dstbf) {
  const int tid = threadIdx.x;
  const int lane = tid & 63;
  const int wid = tid >> 6;
  const int wr = wid >> 1;
  const int wc = wid & 1;
  const int m0 = bx * 64;
  const int n0 = by * 64;
  const int l15 = lane & 15;
  const int kb = lane >> 4;

  const unsigned short* Ar0 = A + (size_t)(m0 + wr * 32 + l15) * 1024 + kb * 8;
  const unsigned short* Ar1 = Ar0 + 16 * 1024;
  const unsigned short* Br0 = B + (size_t)(n0 + wc * 32 + l15) * 1024 + kb * 8;
  const unsigned short* Br1 = Br0 + 16 * 1024;

  f32x4 acc[2][2];
#pragma unroll
  for (int f = 0; f < 2; ++f)
#pragma unroll
    for (int g = 0; g < 2; ++g) acc[f][g] = (f32x4){0.f, 0.f, 0.f, 0.f};

  bf16x8 af[4][2], bq[4][2];
  ldfrag(Ar0, Ar1, Br0, Br1, 0, af[0], bq[0]);
  ldfrag(Ar0, Ar1, Br0, Br1, 1, af[1], bq[1]);
  ldfrag(Ar0, Ar1, Br0, Br1, 2, af[2], bq[2]);

#pragma unroll
  for (int kt = 0; kt < 32; ++kt) {
    const int s = kt & 3;
    if (kt + 3 < 32)
      ldfrag(Ar0, Ar1, Br0, Br1, kt + 3, af[(kt + 3) & 3], bq[(kt + 3) & 3]);
    acc[0][0] = __builtin_amdgcn_mfma_f32_16x16x32_bf16(af[s][0], bq[s][0], acc[0][0], 0, 0, 0);
    acc[0][1] = __builtin_amdgcn_mfma_f32_16x16x32_bf16(af[s][0], bq[s][1], acc[0][1], 0, 0, 0);
    acc[1][0] = __builtin_amdgcn_mfma_f32_16x16x32_bf16(af[s][1], bq[s][0], acc[1][0], 0, 0, 0);
    acc[1][1] = __builtin_amdgcn_mfma_f32_16x16x32_bf16(af[s][1], bq[s][1], acc[1][1], 0, 0, 0);
  }

  // epilogue: C/D layout col = lane&15, row = (lane>>4)*4 + j
#pragma unroll
  for (int f = 0; f < 2; ++f) {
#pragma unroll
    for (int g = 0; g < 2; ++g) {
#pragma unroll
      for (int j = 0; j < 4; ++j) {
        int m = m0 + wr * 32 + f * 16 + kb * 4 + j;
        int n = n0 + wc * 32 + g * 16 + l15;
        size_t idx = (size_t)m * 1024 + n;
        float v = acc[f][g][j];
        if (mode == 0) {                  // raw bf16
          dstbf[idx] = f2b(v);
        } else if (mode == 1) {           // h-stage
          float h = v + bias0[n];
          float thv = tanhf(h);
          float r = h + 0.1f * bias1[n];
          dstf0[idx] = r;
          dstf1[idx] = thv;
          dstbf[idx] = f2b(r);
        } else if (mode == 2) {           // b1v = 11 th + 0.1 c1
          dstbf[idx] = f2b(11.0f * src0[idx] + 0.1f * v);
        } else if (mode == 3) {           // y1v
          dstf0[idx] = v;
          dstbf[idx] = f2b(v);
        } else if (mode == 4) {           // r2u = r1u - 0.1 d1 + 0.1 b2
          float r = src0[idx] - 0.1f * v + 0.1f * bias0[n];
          dstf0[idx] = r;
          dstbf[idx] = f2b(r);
        } else if (mode == 5) {           // b2v = 10 th + y1v + 0.1 c2
          dstbf[idx] = f2b(10.0f * src0[idx] + src1[idx] + 0.1f * v);
        } else if (mode == 7) {           // y2u = r2u - 0.1 d2
          dstbf[idx] = f2b(src0[idx] - 0.1f * v);
        } else if (mode == 8) {           // logits
          dstf0[idx] = v + bias0[n];
        } else {                          // mode 9: Q = I/11 - (0.01/121) P
          float q = (m == n ? (1.0f / 11.0f) : 0.0f) - (0.01f / 121.0f) * v;
          dstbf[idx] = f2b(q);
        }
      }
    }
  }
}

// main-chain GEMM, 512 blocks, XCD-sharded tile map
__global__ __launch_bounds__(256) void k_gemm(
    const unsigned short* __restrict__ A, const unsigned short* __restrict__ B,
    int mode, const float* bias0, const float* bias1,
    const float* src0, const float* src1,
    float* dstf0, float* dstf1, unsigned short* dstbf) {
  const int b = blockIdx.x;
  const int bx = ((b & 7) << 2) | ((b >> 3) & 3);
  const int by = b >> 5;
  gemm64(A, B, bx, by, mode, bias0, bias1, src0, src1, dstf0, dstf1, dstbf);
}

// stage A: G0 (h-stage, blocks 0..511) + QG (Q1,Q2, blocks 512..1023)
__global__ __launch_bounds__(256) void k_stageA(
    const unsigned short* __restrict__ xb, const unsigned short* __restrict__ winb,
    const unsigned short* __restrict__ wtb,
    const float* __restrict__ b_in, const float* __restrict__ b1,
    float* __restrict__ r1u, float* __restrict__ th,
    unsigned short* __restrict__ bfA0, unsigned short* __restrict__ qb) {
  const int b = blockIdx.x;
  if (b < 512) {
    const int bx = ((b & 7) << 2) | ((b >> 3) & 3);
    const int by = b >> 5;
    gemm64(xb, winb, bx, by, 1, b_in, b1, nullptr, nullptr, r1u, th, bfA0);
  } else {
    int r = b - 512;
    const int z = r >> 8;
    r &= 255;
    const int qbx = ((r & 7) << 1) | ((r >> 3) & 1);
    const int qby = (r >> 4) & 15;
    const unsigned short* wt = wtb + (size_t)z * M1;
    gemm64(wt, wt, qbx, qby, 9, nullptr, nullptr, nullptr, nullptr,
           nullptr, nullptr, qb + (size_t)z * M1);
  }
}

// one-dispatch prep: W1/W2 bf16+transpose (blocks 0..2047), x (2048..4095),
// W_in (4096..5119), W_out padded (5120..6143), b_out (6144)
__global__ __launch_bounds__(256) void k_prep(
    const float* __restrict__ x, const float* __restrict__ Win,
    const float* __restrict__ W1, const float* __restrict__ W2,
    const float* __restrict__ Wout, const float* __restrict__ bout,
    unsigned short* __restrict__ xb, unsigned short* __restrict__ winb,
    unsigned short* __restrict__ wb, unsigned short* __restrict__ wtb,
    unsigned short* __restrict__ woutb, float* __restrict__ boutp) {
  __shared__ float tile[32][33];
  const int b = blockIdx.x;
  const int tid = threadIdx.x;
  if (b < 2048) {
    const float* W = (b & 1024) ? W2 : W1;
    unsigned short* Wb = wb + ((size_t)(b >> 10) << 20);
    unsigned short* WTb = wtb + ((size_t)(b >> 10) << 20);
    const int rem = b & 1023;
    const int tbx = rem & 31, tby = rem >> 5;
    const int tx = tid & 31, ty = tid >> 5;
#pragma unroll
    for (int i = ty; i < 32; i += 8) {
      float v = W[(size_t)(tby * 32 + i) * 1024 + tbx * 32 + tx];
      tile[i][tx] = v;
      Wb[(size_t)(tby * 32 + i) * 1024 + tbx * 32 + tx] = f2b(v);
    }
    __syncthreads();
#pragma unroll
    for (int i = ty; i < 32; i += 8)
      WTb[(size_t)(tbx * 32 + i) * 1024 + tby * 32 + tx] = f2b(tile[tx][i]);
  } else if (b < 4096) {
    int i = (b - 2048) * 256 + tid;
    float4 v = ((const float4*)x)[i];
    ((ushort4*)xb)[i] = (ushort4){f2b(v.x), f2b(v.y), f2b(v.z), f2b(v.w)};
  } else if (b < 5120) {
    int i = (b - 4096) * 256 + tid;
    float4 v = ((const float4*)Win)[i];
    ((ushort4*)winb)[i] = (ushort4){f2b(v.x), f2b(v.y), f2b(v.z), f2b(v.w)};
  } else if (b < 6144) {
    int i = (b - 5120) * 256 + tid;
    ushort4 o = (ushort4){0, 0, 0, 0};
    if ((i >> 8) < 1000) {
      float4 v = ((const float4*)Wout)[i];
      o = (ushort4){f2b(v.x), f2b(v.y), f2b(v.z), f2b(v.w)};
    }
    ((ushort4*)woutb)[i] = o;
  } else {
    for (int j = tid; j < 1024; j += 256) boutp[j] = (j < 1000) ? bout[j] : 0.0f;
  }
}

// row softmax over first 1000 cols of 2048x1024 logits -> 2048x1000
__global__ __launch_bounds__(256) void k_softmax(const float* __restrict__ lg,
                                                 float* __restrict__ out) {
  const int r = blockIdx.x;
  const float* p = lg + (size_t)r * 1024;
  float* q = out + (size_t)r * 1000;
  const int tid = threadIdx.x;
  const int lane = tid & 63;
  const int w = tid >> 6;
  __shared__ float redm[4];
  __shared__ float reds[4];
  float m = -3.0e38f;
  for (int i = tid; i < 1000; i += 256) m = fmaxf(m, p[i]);
#pragma unroll
  for (int o = 32; o > 0; o >>= 1) m = fmaxf(m, __shfl_xor(m, o));
  if (lane == 0) redm[w] = m;
  __syncthreads();
  m = fmaxf(fmaxf(redm[0], redm[1]), fmaxf(redm[2], redm[3]));
  float s = 0.0f;
  for (int i = tid; i < 1000; i += 256) {
    float e = __expf(p[i] - m);
    q[i] = e;
    s += e;
  }
#pragma unroll
  for (int o = 32; o > 0; o >>= 1) s += __shfl_xor(s, o);
  if (lane == 0) reds[w] = s;
  __syncthreads();
  float inv = 1.0f / (reds[0] + reds[1] + reds[2] + reds[3]);
  for (int i = tid; i < 1000; i += 256) q[i] *= inv;
}

extern "C" void kernel_launch(void* const* d_in, const int* in_sizes, int n_in,
                              void* d_out, int out_size, void* d_ws, size_t ws_size,
                              hipStream_t stream) {
  const float* x = (const float*)d_in[0];
  const float* W_in = (const float*)d_in[1];
  const float* b_in = (const float*)d_in[2];
  const float* W1 = (const float*)d_in[3];
  const float* b1 = (const float*)d_in[4];
  const float* W2 = (const float*)d_in[5];
  const float* b2 = (const float*)d_in[6];
  const float* W_out = (const float*)d_in[7];
  const float* b_out = (const float*)d_in[8];
  float* out = (float*)d_out;

  const size_t Bm = 2048, U = 1024;
  char* ws = (char*)d_ws;
  size_t off = 0;
  auto alloc = [&](size_t bytes) -> void* {
    void* p = ws + off;
    off += (bytes + 255) & ~(size_t)255;
    return p;
  };
  unsigned short* xb = (unsigned short*)alloc(Bm * U * 2);
  unsigned short* winb = (unsigned short*)alloc((size_t)M1 * 2);
  unsigned short* wb = (unsigned short*)alloc(2 * (size_t)M1 * 2);   // W1,W2
  unsigned short* wtb = (unsigned short*)alloc(2 * (size_t)M1 * 2);  // W1^T,W2^T
  unsigned short* qb = (unsigned short*)alloc(2 * (size_t)M1 * 2);   // Q1,Q2
  unsigned short* woutb = (unsigned short*)alloc((size_t)M1 * 2);
  float* boutp = (float*)alloc(U * 4);
  float* r1u = (float*)alloc(Bm * U * 4);
  float* th = (float*)alloc(Bm * U * 4);
  float* y1v = (float*)alloc(Bm * U * 4);
  float* r2u = (float*)alloc(Bm * U * 4);
  float* lgts = (float*)alloc(Bm * U * 4);
  unsigned short* bfA0 = (unsigned short*)alloc(Bm * U * 2);
  unsigned short* bfA1 = (unsigned short*)alloc(Bm * U * 2);

  k_prep<<<6145, 256, 0, stream>>>(x, W_in, W1, W2, W_out, b_out,
                                   xb, winb, wb, wtb, woutb, boutp);
  // stage A: G0 + QG
  k_stageA<<<1024, 256, 0, stream>>>(xb, winb, wtb, b_in, b1, r1u, th, bfA0, qb);
  // G1: c1 = r1u@W1 -> b1v
  k_gemm<<<512, 256, 0, stream>>>(bfA0, wtb, 2, nullptr, nullptr, th, nullptr,
                                  nullptr, nullptr, bfA1);
  // G2: y1v = b1v@Q1
  k_gemm<<<512, 256, 0, stream>>>(bfA1, qb, 3, nullptr, nullptr, nullptr, nullptr,
                                  y1v, nullptr, bfA0);
  // G3: d1 = y1v@W1^T -> r2u
  k_gemm<<<512, 256, 0, stream>>>(bfA0, wb, 4, b2, nullptr, r1u, nullptr,
                                  r2u, nullptr, bfA1);
  // G4: c2 = r2u@W2 -> b2v
  k_gemm<<<512, 256, 0, stream>>>(bfA1, wtb + M1, 5, nullptr, nullptr, th, y1v,
                                  nullptr, nullptr, bfA0);
  // G5: y2v = b2v@Q2
  k_gemm<<<512, 256, 0, stream>>>(bfA0, qb + M1, 0, nullptr, nullptr, nullptr, nullptr,
                                  nullptr, nullptr, bfA1);
  // G6: d2 = y2v@W2^T -> y2u
  k_gemm<<<512, 256, 0, stream>>>(bfA1, wb + M1, 7, nullptr, nullptr, r2u, nullptr,
                                  nullptr, nullptr, bfA0);
  // G7: logits = y2u@Wout^T + bout
  k_gemm<<<512, 256, 0, stream>>>(bfA0, woutb, 8, boutp, nullptr, nullptr, nullptr,
                                  lgts, nullptr, nullptr);

  k_softmax<<<2048, 256, 0, stream>>>(lgts, out);
}

// Round 6
// 134.190 us; speedup vs baseline: 2.3734x; 2.3734x over previous
//
#include <hip/hip_runtime.h>

// ---------------------------------------------------------------------------
// TransNetSweepingExplRhs — analytic reduction (derivation in R1/R2):
//   h = x@W_in^T + b_in ; th = tanh(h); r1u = h + 0.1 b1
//   Q_i = I/11 - (0.01/121) W_i^T W_i      (1-term Neumann inverse)
//   b1v = 11 th + 0.1 (r1u@W1); y1v = b1v@Q1
//   r2u = r1u - 0.1 (y1v@W1^T) + 0.1 b2
//   b2v = 10 th + y1v + 0.1 (r2u@W2); y2v = b2v@Q2
//   y2u = r2u - 0.1 (y2v@W2^T);  out = softmax(y2u@W_out^T + b_out)
// R6: back to LDS staging (R5's no-LDS was latency-bound: MfmaUtil 5%).
// K-loop = 3-buffer depth-2 pipeline, BK=64, counted vmcnt(4) per phase
// (vmcnt(0) only in last peeled phase), raw s_barrier — loads stay in
// flight across barriers (T3/T4). 8-chunk rotation swizzle on both sides
// (pre-swizzled global source + swizzled ds_read) -> conflict-free.
// XCD-sharded tile map (b&7 = XCD slice) keeps per-XCD set L2-resident.
// ---------------------------------------------------------------------------

typedef short bf16x8 __attribute__((ext_vector_type(8)));
typedef float f32x4 __attribute__((ext_vector_type(4)));

#define M1 1048576

__device__ __forceinline__ unsigned short f2b(float f) {
  union { float f; unsigned int u; } v; v.f = f;
  unsigned int u = v.u;
  return (unsigned short)((u + 0x7FFFu + ((u >> 16) & 1u)) >> 16);
}

__device__ __forceinline__ void gload16(const void* g, void* l) {
  __builtin_amdgcn_global_load_lds(
      (const __attribute__((address_space(1))) unsigned int*)g,
      (__attribute__((address_space(3))) unsigned int*)l, 16, 0, 0);
}

// C[m,n] = sum_k A[m,k]*B[n,k], K=1024, tile 64x64 at (bx,by), BK=64.
// LDS layout per k-tile: [64 rows][8 chunks of 16B], chunk stored at
// position (c + row) & 7  (rotation swizzle). gload_lds dest is linear;
// the global SOURCE is pre-swizzled: thread t, pass p reads chunk
// ((t&7) - (t>>3)) & 7 of row p*32 + (t>>3).
__device__ __forceinline__ void gemm64(
    const unsigned short* __restrict__ A, const unsigned short* __restrict__ B,
    int bx, int by, int mode,
    const float* bias0, const float* bias1,
    const float* src0, const float* src1,
    float* dstf0, float* dstf1, unsigned short* dstbf,
    short (*As)[4096], short (*Bs)[4096]) {
  const int tid = threadIdx.x;
  const int lane = tid & 63;
  const int wid = tid >> 6;
  const int wr = wid >> 1;
  const int wc = wid & 1;
  const int m0 = bx * 64;
  const int n0 = by * 64;
  const int l15 = lane & 15;
  const int kb = lane >> 4;

  // staging source (pre-swizzled)
  const int sr = tid >> 3;                       // row within pass (0..31)
  const int sg = ((tid & 7) - (tid >> 3)) & 7;   // source chunk
  const unsigned short* Asrc = A + (size_t)(m0 + sr) * 1024 + sg * 8;
  const unsigned short* Bsrc = B + (size_t)(n0 + sr) * 1024 + sg * 8;
  const int o0 = tid * 8;          // LDS short offset, pass 0
  const int o1 = 2048 + tid * 8;   // pass 1 (rows 32..63)

  f32x4 acc[2][2];
#pragma unroll
  for (int f = 0; f < 2; ++f)
#pragma unroll
    for (int g = 0; g < 2; ++g) acc[f][g] = (f32x4){0.f, 0.f, 0.f, 0.f};

#define STAGE(kt, buf)                                       \
  do {                                                       \
    gload16(Asrc + (kt) * 64, &As[(buf)][o0]);               \
    gload16(Asrc + 32 * 1024 + (kt) * 64, &As[(buf)][o1]);   \
    gload16(Bsrc + (kt) * 64, &Bs[(buf)][o0]);               \
    gload16(Bsrc + 32 * 1024 + (kt) * 64, &Bs[(buf)][o1]);   \
  } while (0)

  STAGE(0, 0);
  STAGE(1, 1);

#pragma unroll
  for (int t = 0; t < 16; ++t) {
    if (t < 15) {
      asm volatile("s_waitcnt vmcnt(4)" ::: "memory");
    } else {
      asm volatile("s_waitcnt vmcnt(0)" ::: "memory");
    }
    __builtin_amdgcn_sched_barrier(0);
    __builtin_amdgcn_s_barrier();
    __builtin_amdgcn_sched_barrier(0);
    if (t + 2 < 16) STAGE(t + 2, (t + 2) % 3);
    const int cb = t % 3;
    bf16x8 av[2][2], bv[2][2];
#pragma unroll
    for (int f = 0; f < 2; ++f) {
      const int ra = wr * 32 + f * 16 + l15;
#pragma unroll
      for (int ks = 0; ks < 2; ++ks) {
        const int qa = (ks * 4 + kb + l15) & 7;
        av[f][ks] = *reinterpret_cast<const bf16x8*>(&As[cb][ra * 64 + qa * 8]);
      }
    }
#pragma unroll
    for (int g = 0; g < 2; ++g) {
      const int rb = wc * 32 + g * 16 + l15;
#pragma unroll
      for (int ks = 0; ks < 2; ++ks) {
        const int qb = (ks * 4 + kb + l15) & 7;
        bv[g][ks] = *reinterpret_cast<const bf16x8*>(&Bs[cb][rb * 64 + qb * 8]);
      }
    }
#pragma unroll
    for (int ks = 0; ks < 2; ++ks)
#pragma unroll
      for (int f = 0; f < 2; ++f)
#pragma unroll
        for (int g = 0; g < 2; ++g)
          acc[f][g] = __builtin_amdgcn_mfma_f32_16x16x32_bf16(av[f][ks], bv[g][ks], acc[f][g], 0, 0, 0);
  }
#undef STAGE

  // epilogue: C/D layout col = lane&15, row = (lane>>4)*4 + j
#pragma unroll
  for (int f = 0; f < 2; ++f) {
#pragma unroll
    for (int g = 0; g < 2; ++g) {
#pragma unroll
      for (int j = 0; j < 4; ++j) {
        int m = m0 + wr * 32 + f * 16 + kb * 4 + j;
        int n = n0 + wc * 32 + g * 16 + l15;
        size_t idx = (size_t)m * 1024 + n;
        float v = acc[f][g][j];
        if (mode == 0) {                  // raw bf16
          dstbf[idx] = f2b(v);
        } else if (mode == 1) {           // h-stage
          float h = v + bias0[n];
          float thv = tanhf(h);
          float r = h + 0.1f * bias1[n];
          dstf0[idx] = r;
          dstf1[idx] = thv;
          dstbf[idx] = f2b(r);
        } else if (mode == 2) {           // b1v = 11 th + 0.1 c1
          dstbf[idx] = f2b(11.0f * src0[idx] + 0.1f * v);
        } else if (mode == 3) {           // y1v
          dstf0[idx] = v;
          dstbf[idx] = f2b(v);
        } else if (mode == 4) {           // r2u = r1u - 0.1 d1 + 0.1 b2
          float r = src0[idx] - 0.1f * v + 0.1f * bias0[n];
          dstf0[idx] = r;
          dstbf[idx] = f2b(r);
        } else if (mode == 5) {           // b2v = 10 th + y1v + 0.1 c2
          dstbf[idx] = f2b(10.0f * src0[idx] + src1[idx] + 0.1f * v);
        } else if (mode == 7) {           // y2u = r2u - 0.1 d2
          dstbf[idx] = f2b(src0[idx] - 0.1f * v);
        } else if (mode == 8) {           // logits
          dstf0[idx] = v + bias0[n];
        } else {                          // mode 9: Q = I/11 - (0.01/121) P
          float q = (m == n ? (1.0f / 11.0f) : 0.0f) - (0.01f / 121.0f) * v;
          dstbf[idx] = f2b(q);
        }
      }
    }
  }
}

// main-chain GEMM, 512 blocks, XCD-sharded tile map
__global__ __launch_bounds__(256) void k_gemm(
    const unsigned short* __restrict__ A, const unsigned short* __restrict__ B,
    int mode, const float* bias0, const float* bias1,
    const float* src0, const float* src1,
    float* dstf0, float* dstf1, unsigned short* dstbf) {
  __shared__ short As[3][4096];
  __shared__ short Bs[3][4096];
  const int b = blockIdx.x;
  const int bx = ((b & 7) << 2) | ((b >> 3) & 3);
  const int by = b >> 5;
  gemm64(A, B, bx, by, mode, bias0, bias1, src0, src1, dstf0, dstf1, dstbf, As, Bs);
}

// stage A: G0 (h-stage, blocks 0..511) + QG (Q1,Q2, blocks 512..1023)
__global__ __launch_bounds__(256) void k_stageA(
    const unsigned short* __restrict__ xb, const unsigned short* __restrict__ winb,
    const unsigned short* __restrict__ wtb,
    const float* __restrict__ b_in, const float* __restrict__ b1,
    float* __restrict__ r1u, float* __restrict__ th,
    unsigned short* __restrict__ bfA0, unsigned short* __restrict__ qb) {
  __shared__ short As[3][4096];
  __shared__ short Bs[3][4096];
  const int b = blockIdx.x;
  if (b < 512) {
    const int bx = ((b & 7) << 2) | ((b >> 3) & 3);
    const int by = b >> 5;
    gemm64(xb, winb, bx, by, 1, b_in, b1, nullptr, nullptr, r1u, th, bfA0, As, Bs);
  } else {
    int r = b - 512;
    const int z = r >> 8;
    r &= 255;
    const int qbx = ((r & 7) << 1) | ((r >> 3) & 1);
    const int qby = (r >> 4) & 15;
    const unsigned short* wt = wtb + (size_t)z * M1;
    gemm64(wt, wt, qbx, qby, 9, nullptr, nullptr, nullptr, nullptr,
           nullptr, nullptr, qb + (size_t)z * M1, As, Bs);
  }
}

// one-dispatch prep: W1/W2 bf16+transpose (blocks 0..2047), x (2048..4095),
// W_in (4096..5119), W_out padded (5120..6143), b_out (6144)
__global__ __launch_bounds__(256) void k_prep(
    const float* __restrict__ x, const float* __restrict__ Win,
    const float* __restrict__ W1, const float* __restrict__ W2,
    const float* __restrict__ Wout, const float* __restrict__ bout,
    unsigned short* __restrict__ xb, unsigned short* __restrict__ winb,
    unsigned short* __restrict__ wb, unsigned short* __restrict__ wtb,
    unsigned short* __restrict__ woutb, float* __restrict__ boutp) {
  __shared__ float tile[32][33];
  const int b = blockIdx.x;
  const int tid = threadIdx.x;
  if (b < 2048) {
    const float* W = (b & 1024) ? W2 : W1;
    unsigned short* Wb = wb + ((size_t)(b >> 10) << 20);
    unsigned short* WTb = wtb + ((size_t)(b >> 10) << 20);
    const int rem = b & 1023;
    const int tbx = rem & 31, tby = rem >> 5;
    const int tx = tid & 31, ty = tid >> 5;
#pragma unroll
    for (int i = ty; i < 32; i += 8) {
      float v = W[(size_t)(tby * 32 + i) * 1024 + tbx * 32 + tx];
      tile[i][tx] = v;
      Wb[(size_t)(tby * 32 + i) * 1024 + tbx * 32 + tx] = f2b(v);
    }
    __syncthreads();
#pragma unroll
    for (int i = ty; i < 32; i += 8)
      WTb[(size_t)(tbx * 32 + i) * 1024 + tby * 32 + tx] = f2b(tile[tx][i]);
  } else if (b < 4096) {
    int i = (b - 2048) * 256 + tid;
    float4 v = ((const float4*)x)[i];
    ((ushort4*)xb)[i] = (ushort4){f2b(v.x), f2b(v.y), f2b(v.z), f2b(v.w)};
  } else if (b < 5120) {
    int i = (b - 4096) * 256 + tid;
    float4 v = ((const float4*)Win)[i];
    ((ushort4*)winb)[i] = (ushort4){f2b(v.x), f2b(v.y), f2b(v.z), f2b(v.w)};
  } else if (b < 6144) {
    int i = (b - 5120) * 256 + tid;
    ushort4 o = (ushort4){0, 0, 0, 0};
    if ((i >> 8) < 1000) {
      float4 v = ((const float4*)Wout)[i];
      o = (ushort4){f2b(v.x), f2b(v.y), f2b(v.z), f2b(v.w)};
    }
    ((ushort4*)woutb)[i] = o;
  } else {
    for (int j = tid; j < 1024; j += 256) boutp[j] = (j < 1000) ? bout[j] : 0.0f;
  }
}

// row softmax over first 1000 cols of 2048x1024 logits -> 2048x1000
__global__ __launch_bounds__(256) void k_softmax(const float* __restrict__ lg,
                                                 float* __restrict__ out) {
  const int r = blockIdx.x;
  const float* p = lg + (size_t)r * 1024;
  float* q = out + (size_t)r * 1000;
  const int tid = threadIdx.x;
  const int lane = tid & 63;
  const int w = tid >> 6;
  __shared__ float redm[4];
  __shared__ float reds[4];
  float m = -3.0e38f;
  for (int i = tid; i < 1000; i += 256) m = fmaxf(m, p[i]);
#pragma unroll
  for (int o = 32; o > 0; o >>= 1) m = fmaxf(m, __shfl_xor(m, o));
  if (lane == 0) redm[w] = m;
  __syncthreads();
  m = fmaxf(fmaxf(redm[0], redm[1]), fmaxf(redm[2], redm[3]));
  float s = 0.0f;
  for (int i = tid; i < 1000; i += 256) {
    float e = __expf(p[i] - m);
    q[i] = e;
    s += e;
  }
#pragma unroll
  for (int o = 32; o > 0; o >>= 1) s += __shfl_xor(s, o);
  if (lane == 0) reds[w] = s;
  __syncthreads();
  float inv = 1.0f / (reds[0] + reds[1] + reds[2] + reds[3]);
  for (int i = tid; i < 1000; i += 256) q[i] *= inv;
}

extern "C" void kernel_launch(void* const* d_in, const int* in_sizes, int n_in,
                              void* d_out, int out_size, void* d_ws, size_t ws_size,
                              hipStream_t stream) {
  const float* x = (const float*)d_in[0];
  const float* W_in = (const float*)d_in[1];
  const float* b_in = (const float*)d_in[2];
  const float* W1 = (const float*)d_in[3];
  const float* b1 = (const float*)d_in[4];
  const float* W2 = (const float*)d_in[5];
  const float* b2 = (const float*)d_in[6];
  const float* W_out = (const float*)d_in[7];
  const float* b_out = (const float*)d_in[8];
  float* out = (float*)d_out;

  const size_t Bm = 2048, U = 1024;
  char* ws = (char*)d_ws;
  size_t off = 0;
  auto alloc = [&](size_t bytes) -> void* {
    void* p = ws + off;
    off += (bytes + 255) & ~(size_t)255;
    return p;
  };
  unsigned short* xb = (unsigned short*)alloc(Bm * U * 2);
  unsigned short* winb = (unsigned short*)alloc((size_t)M1 * 2);
  unsigned short* wb = (unsigned short*)alloc(2 * (size_t)M1 * 2);   // W1,W2
  unsigned short* wtb = (unsigned short*)alloc(2 * (size_t)M1 * 2);  // W1^T,W2^T
  unsigned short* qb = (unsigned short*)alloc(2 * (size_t)M1 * 2);   // Q1,Q2
  unsigned short* woutb = (unsigned short*)alloc((size_t)M1 * 2);
  float* boutp = (float*)alloc(U * 4);
  float* r1u = (float*)alloc(Bm * U * 4);
  float* th = (float*)alloc(Bm * U * 4);
  float* y1v = (float*)alloc(Bm * U * 4);
  float* r2u = (float*)alloc(Bm * U * 4);
  float* lgts = (float*)alloc(Bm * U * 4);
  unsigned short* bfA0 = (unsigned short*)alloc(Bm * U * 2);
  unsigned short* bfA1 = (unsigned short*)alloc(Bm * U * 2);

  k_prep<<<6145, 256, 0, stream>>>(x, W_in, W1, W2, W_out, b_out,
                                   xb, winb, wb, wtb, woutb, boutp);
  // stage A: G0 + QG
  k_stageA<<<1024, 256, 0, stream>>>(xb, winb, wtb, b_in, b1, r1u, th, bfA0, qb);
  // G1: c1 = r1u@W1 -> b1v
  k_gemm<<<512, 256, 0, stream>>>(bfA0, wtb, 2, nullptr, nullptr, th, nullptr,
                                  nullptr, nullptr, bfA1);
  // G2: y1v = b1v@Q1
  k_gemm<<<512, 256, 0, stream>>>(bfA1, qb, 3, nullptr, nullptr, nullptr, nullptr,
                                  y1v, nullptr, bfA0);
  // G3: d1 = y1v@W1^T -> r2u
  k_gemm<<<512, 256, 0, stream>>>(bfA0, wb, 4, b2, nullptr, r1u, nullptr,
                                  r2u, nullptr, bfA1);
  // G4: c2 = r2u@W2 -> b2v
  k_gemm<<<512, 256, 0, stream>>>(bfA1, wtb + M1, 5, nullptr, nullptr, th, y1v,
                                  nullptr, nullptr, bfA0);
  // G5: y2v = b2v@Q2
  k_gemm<<<512, 256, 0, stream>>>(bfA0, qb + M1, 0, nullptr, nullptr, nullptr, nullptr,
                                  nullptr, nullptr, bfA1);
  // G6: d2 = y2v@W2^T -> y2u
  k_gemm<<<512, 256, 0, stream>>>(bfA1, wb + M1, 7, nullptr, nullptr, r2u, nullptr,
                                  nullptr, nullptr, bfA0);
  // G7: logits = y2u@Wout^T + bout
  k_gemm<<<512, 256, 0, stream>>>(bfA0, woutb, 8, boutp, nullptr, nullptr, nullptr,
                                  lgts, nullptr, nullptr);

  k_softmax<<<2048, 256, 0, stream>>>(lgts, out);
}